// Round 7
// baseline (1547.232 us; speedup 1.0000x reference)
//
#include <hip/hip_runtime.h>

// ---------------------------------------------------------------------------
// GRU (T=256, B=1024, IN=128, H=256) + per-step BatchNorm, MI355X.
// R12->R13: gru reverted to the R9/R11 residency map (streamed in/hn kt4-7;
// R12's zero-stream 48-pin layout REGRESSED: FETCH +3.5MB, WRITE +7MB, +56us
// -> residency search closed). Two new levers:
//   (1) gru: even/odd-kt split accumulator chains (16 chains depth-4 instead
//       of 8 chains depth-8; +32 accum VGPRs, memory pattern untouched).
//   (2) pack_all: fold parallelism 2x (ii-loop split across thread pairs,
//       LDS combine) -> fold blocks 257, ~512 FMA/thread.
// yfused epilogue (R11-proven) untouched.
// ---------------------------------------------------------------------------

typedef _Float16 half8 __attribute__((ext_vector_type(8)));
typedef float floatx4 __attribute__((ext_vector_type(4)));
typedef unsigned uintx4 __attribute__((ext_vector_type(4)));

#define EPS_BN 1e-5f

// ws layout (bytes):
//   [0,       524288)   wc: folded gate weights, 16 cgs x 32 tiles x 1 KB
//   [524288, 1114112)   w0: step-0 weights, 16 cgs x 36 tiles x 1 KB
//   [1114112,1179648)   wl: W_lin B-frags, 64 tiles x 1 KB
//   [1179648,1183744)   bias0: 256 x float4
//   [1183744,1187840)   bc: 256 x float4 folded biases
#define WS_WC 0
#define WS_W0 524288
#define WS_WL 1114112
#define WS_B0 1179648
#define WS_BC 1183744

static __device__ __forceinline__ unsigned short f2h(float f) {
    union { _Float16 h; unsigned short u; } v;
    v.h = (_Float16)f;                      // v_cvt_f16_f32, RNE
    return v.u;
}
static __device__ __forceinline__ unsigned pack2h(float a, float b) {
    return (unsigned)f2h(a) | ((unsigned)f2h(b) << 16);
}
static __device__ __forceinline__ float2 up2(unsigned u) {
    union { unsigned v; _Float16 h[2]; } x; x.v = u;
    return make_float2((float)x.h[0], (float)x.h[1]);
}
static __device__ __forceinline__ half8 as_h8(uint4 v) {
    union { uint4 u; half8 h; } x; x.u = v; return x.h;
}
// Load a 16B weight fragment and force it into AGPRs (opaque, non-remat).
static __device__ __forceinline__ half8 ld_agpr(const uint4* p) {
    uintx4 v = *(const uintx4*)p;
    asm volatile("; wpin" : "+a"(v));
    union { uintx4 u; half8 h; } x; x.u = v; return x.h;
}
// Fast activations: v_rcp_f32 + v_exp_f32 (1 ulp each).
static __device__ __forceinline__ float sigm(float x) {
    return __builtin_amdgcn_rcpf(1.0f + __builtin_amdgcn_exp2f(-1.442695041f * x));
}
static __device__ __forceinline__ float tanh_fast(float x) {
    return 1.0f - 2.0f * __builtin_amdgcn_rcpf(1.0f + __builtin_amdgcn_exp2f(2.885390082f * x));
}
// Workgroup barrier that drains LDS only (no vmcnt(0) store-drain).
static __device__ __forceinline__ void bar_lgkm() {
    asm volatile("s_waitcnt lgkmcnt(0)\n\ts_barrier" ::: "memory");
}
#define MFMA16(A, B, C) __builtin_amdgcn_mfma_f32_16x16x32_f16((A), (B), (C), 0, 0, 0)

// ---------------------------------------------------------------------------
// pack_all: [blocks 0..160] original weights -> w0 tiles + wl + bias0;
// [blocks 161..417] folded weights -> wc tiles (ii-split x2, LDS combine)
// + folded biases bc. B-frag 16x16x32: lane l holds B[n0+(l&15)][k0+(l>>4)*8+j].
// ---------------------------------------------------------------------------
__global__ void pack_all_kernel(const float* __restrict__ W_ih, const float* __restrict__ W_hh,
                                const float* __restrict__ W_lin, const float* __restrict__ b_ih,
                                const float* __restrict__ b_hh, const float* __restrict__ b_lin,
                                uint4* __restrict__ w0, uint4* __restrict__ wl,
                                float4* __restrict__ bias0,
                                uint4* __restrict__ wc, float4* __restrict__ bc)
{
    __shared__ float sh[256][8];
    if (blockIdx.x < 161) {
        int i = blockIdx.x * 256 + threadIdx.x;
        if (i < 36864) {                       // 576 w0 tiles x 64 lanes
            int lane = i & 63, tile = i >> 6;
            int w = tile / 36, rem = tile - w * 36;
            int g = rem / 12, kt = rem - g * 12;
            int n = g * 256 + (w << 4) + (lane & 15);
            int k0 = (kt << 5) + ((lane >> 4) << 3);
            const float* p = (k0 < 128) ? (W_ih + n * 128 + k0)
                                        : (W_hh + n * 256 + (k0 - 128));
            unsigned short h[8];
            #pragma unroll
            for (int j = 0; j < 8; ++j) h[j] = f2h(p[j]);
            uint4 v;
            v.x = (unsigned)h[0] | ((unsigned)h[1] << 16);
            v.y = (unsigned)h[2] | ((unsigned)h[3] << 16);
            v.z = (unsigned)h[4] | ((unsigned)h[5] << 16);
            v.w = (unsigned)h[6] | ((unsigned)h[7] << 16);
            w0[i] = v;
        } else if (i < 40960) {                // 64 wl tiles x 64 lanes
            int i2 = i - 36864;
            int lane = i2 & 63, tile = i2 >> 6;        // tile = nt*8 + kt
            int n = (tile >> 3) * 16 + (lane & 15);
            int k0 = ((tile & 7) << 5) + ((lane >> 4) << 3);
            const float* p = W_lin + n * 256 + k0;
            unsigned short h[8];
            #pragma unroll
            for (int j = 0; j < 8; ++j) h[j] = f2h(p[j]);
            uint4 v;
            v.x = (unsigned)h[0] | ((unsigned)h[1] << 16);
            v.y = (unsigned)h[2] | ((unsigned)h[3] << 16);
            v.z = (unsigned)h[4] | ((unsigned)h[5] << 16);
            v.w = (unsigned)h[6] | ((unsigned)h[7] << 16);
            wl[i2] = v;
        } else if (i < 41216) {
            int cb = i - 40960;
            bias0[cb] = make_float4(b_ih[cb] + b_hh[cb],
                                    b_ih[256 + cb] + b_hh[256 + cb],
                                    b_ih[512 + cb], b_hh[512 + cb]);
        }
        return;
    }
    int i = (blockIdx.x - 161) * 256 + threadIdx.x;
    if (i < 65536) {                       // 512 wc tiles x 64 lanes x 2 halves
        const int tid  = threadIdx.x;
        const int lane = i & 63;
        const int half = (i >> 6) & 1;     // == (tid >> 6) & 1 (256-aligned)
        const int tile = i >> 7;
        int w = tile >> 5, r = tile & 31;
        int g = r >> 3, kt = r & 7;
        int c = (w << 4) + (lane & 15);
        int k0 = (kt << 5) + ((lane >> 4) << 3);
        float s[8];
        #pragma unroll
        for (int j = 0; j < 8; ++j) s[j] = 0.0f;
        if (g == 3) {
            if (half == 0) {
                #pragma unroll
                for (int j = 0; j < 8; ++j) s[j] = W_hh[(512 + c) * 256 + k0 + j];
            }
        } else {
            int row = g * 256 + c;
            const float* wi = W_ih + row * 128 + (half << 6);
            for (int ii = 0; ii < 64; ++ii) {
                float wv = wi[ii];
                const float* wrow = W_lin + ((half << 6) + ii) * 256 + k0;
                #pragma unroll
                for (int j = 0; j < 8; ++j) s[j] += wv * wrow[j];
            }
            if (g < 2 && half == 0) {
                #pragma unroll
                for (int j = 0; j < 8; ++j) s[j] += W_hh[row * 256 + k0 + j];
            }
        }
        #pragma unroll
        for (int j = 0; j < 8; ++j) sh[tid][j] = s[j];
        __syncthreads();
        if (half == 0) {
            #pragma unroll
            for (int j = 0; j < 8; ++j) s[j] += sh[tid + 64][j];
            unsigned short h[8];
            #pragma unroll
            for (int j = 0; j < 8; ++j) h[j] = f2h(s[j]);
            uint4 v;
            v.x = (unsigned)h[0] | ((unsigned)h[1] << 16);
            v.y = (unsigned)h[2] | ((unsigned)h[3] << 16);
            v.z = (unsigned)h[4] | ((unsigned)h[5] << 16);
            v.w = (unsigned)h[6] | ((unsigned)h[7] << 16);
            wc[tile * 64 + lane] = v;
        }
    } else if (i < 65792) {
        int c = i - 65536;
        float d0 = 0.f, d1 = 0.f, d2 = 0.f;
        for (int ii = 0; ii < 128; ++ii) {
            float bl = b_lin[ii];
            d0 += bl * W_ih[c * 128 + ii];
            d1 += bl * W_ih[(256 + c) * 128 + ii];
            d2 += bl * W_ih[(512 + c) * 128 + ii];
        }
        bc[c] = make_float4(b_ih[c] + b_hh[c] + d0,
                            b_ih[256 + c] + b_hh[256 + c] + d1,
                            b_ih[512 + c] + d2,
                            b_hh[512 + c]);
    }
}

// ---------------------------------------------------------------------------
// Recurrence: 64 blocks x 512 thr (8 waves, 2/SIMD). Block owns 16 batch
// rows; wave w owns col-groups {w, w+8} (cols c0=w*16.., c1=128+w*16..).
// Residency per wave (R9-proven map):
//   AGPR 32: r kt0-7, z kt0-7, both col-groups   (128 AGPRs, asm "+a" pinned)
//   LDS  16: in kt0-3, hn kt0-3, both col-groups (first-used kt<4)
//   streamed 16/step: in kt4-7, hn kt4-7 (first use kt=4 -> >=4-iter lead)
// R13: gate accumulators split into even/odd-kt chains (depth 4 + final add).
// LDS (uint4): [0,1024) h-frag dbuf | [1024,1280) xbuf | [1280,9472)
// per-wave weight tiles (16/wave). One lgkm-only barrier per step.
// ---------------------------------------------------------------------------
__global__ __launch_bounds__(512, 2) void gru_kernel(
    const float* __restrict__ inputs,
    const float* __restrict__ hidden,
    const uint4* __restrict__ wc,
    const uint4* __restrict__ w0,
    const float4* __restrict__ bias0,
    const float4* __restrict__ bcp,
    float* __restrict__ out)
{
    __shared__ uint4 lds[9472];            // 151552 B

    const int tid  = threadIdx.x;
    const int lane = tid & 63;
    const int w    = tid >> 6;             // wave 0..7
    const int quad = lane >> 4;
    const int nc   = lane & 15;
    const int r0   = blockIdx.x << 4;
    const int c0   = (w << 4) + nc;
    const int c1   = 128 + c0;
    const float4 bc0 = bcp[c0];
    const float4 bc1 = bcp[c1];
    const uint4* wcw0 = wc + (size_t)w * 2048;        // 32 tiles * 64
    const uint4* wcw1 = wc + (size_t)(w + 8) * 2048;

    // ---- AGPR-pinned tiles: r kt0-7, z kt0-7 for both col-groups
    half8 wr0[8], wz0[8], wr1[8], wz1[8];
    #pragma unroll
    for (int kt = 0; kt < 8; ++kt) {
        wr0[kt] = ld_agpr(&wcw0[kt * 64 + lane]);
        wz0[kt] = ld_agpr(&wcw0[(8 + kt) * 64 + lane]);
        wr1[kt] = ld_agpr(&wcw1[kt * 64 + lane]);
        wz1[kt] = ld_agpr(&wcw1[(8 + kt) * 64 + lane]);
    }

    // ---- LDS-resident tiles: in kt0-3 (tiles 16-19), hn kt0-3 (tiles 24-27)
    // slot layout per cg: [0-3]=in kt0-3, [4-7]=hn kt0-3; cg1 at +512.
    const int wbase = 1280 + (w << 10);
    #pragma unroll
    for (int i = 0; i < 4; ++i) {
        lds[wbase + (i << 6) + lane]             = wcw0[(16 + i) * 64 + lane];
        lds[wbase + ((4 + i) << 6) + lane]       = wcw0[(24 + i) * 64 + lane];
        lds[wbase + 512 + (i << 6) + lane]       = wcw1[(16 + i) * 64 + lane];
        lds[wbase + 512 + ((4 + i) << 6) + lane] = wcw1[(24 + i) * 64 + lane];
    }

    // fp32 master hidden state: rows quad*4+d; [0..3]=c0, [4..7]=c1
    float hreg[8];
    #pragma unroll
    for (int d = 0; d < 4; ++d) {
        hreg[d]     = hidden[(r0 + (quad << 2) + d) * 256 + c0];
        hreg[4 + d] = hidden[(r0 + (quad << 2) + d) * 256 + c1];
    }

    // A-frag write addressing: A[m][k]: kt=k>>5, k'=k&31,
    // frag lane=(k'>>3)*16+m, j=k'&7; u16 idx=(kt*64+lane_f)*8+j
    unsigned short* lds_u16 = (unsigned short*)lds;
    const int kp  = ((w & 1) << 4) + nc;
    const int lf  = ((kp >> 3) << 4) + (quad << 2);
    const int hfb0 = (((w >> 1) * 64 + lf) << 3) + (kp & 7);
    const int hfb1 = (((4 + (w >> 1)) * 64 + lf) << 3) + (kp & 7);

    // init h(0) frags -> buf0
    for (int idx = tid; idx < 2048; idx += 512) {
        int ktl = idx >> 8;
        int rem = idx & 255;
        int lfr = rem >> 2, jg = rem & 3;
        int m = lfr & 15;
        int hc = ktl * 32 + (lfr >> 4) * 8 + jg * 2;
        const float* p = hidden + (r0 + m) * 256 + hc;
        unsigned pk = (unsigned)f2h(p[0]) | ((unsigned)f2h(p[1]) << 16);
        ((unsigned*)lds)[(ktl * 64 + lfr) * 4 + jg] = pk;
    }
    // init x frags -> xbuf
    for (int idx = tid; idx < 1024; idx += 512) {
        int kt = idx >> 8, lfr = (idx >> 2) & 63, jg = idx & 3;
        int m = lfr & 15;
        int k0 = (kt << 5) + ((lfr >> 4) << 3) + (jg << 1);
        const float* p = inputs + (r0 + m) * 128 + k0;
        unsigned pk = (unsigned)f2h(p[0]) | ((unsigned)f2h(p[1]) << 16);
        ((unsigned*)lds)[(1024 + (kt << 6) + lfr) * 4 + jg] = pk;
    }
    __syncthreads();

    unsigned short* Hout = (unsigned short*)out;

    // ---- t = 0: K=384 on [x|h] with original w0 (streamed once)
    {
        #pragma unroll
        for (int g2 = 0; g2 < 2; ++g2) {
            const uint4* ww = w0 + (size_t)(g2 ? (w + 8) : w) * 2304;  // 36*64
            floatx4 ar = {0.f,0.f,0.f,0.f}, az = {0.f,0.f,0.f,0.f};
            floatx4 ain = {0.f,0.f,0.f,0.f}, ahn = {0.f,0.f,0.f,0.f};
            #pragma unroll
            for (int kt = 0; kt < 12; ++kt) {
                half8 A = as_h8(kt < 4 ? lds[1024 + (kt << 6) + lane]
                                       : lds[((kt - 4) << 6) + lane]);
                ar = MFMA16(A, as_h8(ww[kt * 64 + lane]), ar);
                az = MFMA16(A, as_h8(ww[(12 + kt) * 64 + lane]), az);
                if (kt < 4)
                    ain = MFMA16(A, as_h8(ww[(24 + kt) * 64 + lane]), ain);
                else
                    ahn = MFMA16(A, as_h8(ww[(24 + kt) * 64 + lane]), ahn);
            }
            const int cc = g2 ? c1 : c0;
            const int hfb = g2 ? hfb1 : hfb0;
            float4 b0 = bias0[cc];
            #pragma unroll
            for (int d = 0; d < 4; ++d) {
                float rr = sigm(ar[d] + b0.x);
                float zz = sigm(az[d] + b0.y);
                float nn = tanh_fast(ain[d] + b0.z + rr * (ahn[d] + b0.w));
                float hnew = (1.0f - zz) * nn + zz * hreg[(g2 << 2) + d];
                hreg[(g2 << 2) + d] = hnew;
                unsigned short hu = f2h(hnew);
                lds_u16[4096 + hfb + (d << 3)] = hu;      // buf1
                Hout[((size_t)(r0 + (quad << 2) + d) << 8) + cc] = hu;
            }
        }
        bar_lgkm();
    }

    for (int t = 1; t < 256; ++t) {
        const int rb   = (t & 1) << 9;                 // read buf (uint4)
        const int wb16 = (((t + 1) & 1) << 9) << 3;    // write buf (u16)

        // opaque per-iteration pointers: streamed tiles cannot be hoisted
        const uint4* s0p = wcw0 + lane;
        const uint4* s1p = wcw1 + lane;
        asm("" : "+v"(s0p), "+v"(s1p));

        // streamed tiles: in kt4-7 (tiles 20-23), hn kt4-7 (tiles 28-31).
        // Batches at top and kt=1,2,3; first consumer kt=4 -> >=4-iter lead.
        uint4 si0[4], sh0[4], si1[4], sh1[4];
        si0[0] = s0p[20 * 64]; sh0[0] = s0p[28 * 64];
        si1[0] = s1p[20 * 64]; sh1[0] = s1p[28 * 64];

        // even/odd-kt split accumulator chains (depth 4 each)
        floatx4 ar0e = {0.f,0.f,0.f,0.f}, ar0o = {0.f,0.f,0.f,0.f};
        floatx4 az0e = {0.f,0.f,0.f,0.f}, az0o = {0.f,0.f,0.f,0.f};
        floatx4 ai0e = {0.f,0.f,0.f,0.f}, ai0o = {0.f,0.f,0.f,0.f};
        floatx4 ah0e = {0.f,0.f,0.f,0.f}, ah0o = {0.f,0.f,0.f,0.f};
        floatx4 ar1e = {0.f,0.f,0.f,0.f}, ar1o = {0.f,0.f,0.f,0.f};
        floatx4 az1e = {0.f,0.f,0.f,0.f}, az1o = {0.f,0.f,0.f,0.f};
        floatx4 ai1e = {0.f,0.f,0.f,0.f}, ai1o = {0.f,0.f,0.f,0.f};
        floatx4 ah1e = {0.f,0.f,0.f,0.f}, ah1o = {0.f,0.f,0.f,0.f};

        #pragma unroll
        for (int kt = 0; kt < 8; ++kt) {
            half8 A = as_h8(lds[rb + (kt << 6) + lane]);
            if (kt == 1) {
                si0[1] = s0p[21 * 64]; sh0[1] = s0p[29 * 64];
                si1[1] = s1p[21 * 64]; sh1[1] = s1p[29 * 64];
            }
            if (kt == 2) {
                si0[2] = s0p[22 * 64]; sh0[2] = s0p[30 * 64];
                si1[2] = s1p[22 * 64]; sh1[2] = s1p[30 * 64];
            }
            if (kt == 3) {
                si0[3] = s0p[23 * 64]; sh0[3] = s0p[31 * 64];
                si1[3] = s1p[23 * 64]; sh1[3] = s1p[31 * 64];
            }
            half8 Bi0 = (kt < 4) ? as_h8(lds[wbase + (kt << 6) + lane])
                                 : as_h8(si0[kt - 4]);
            half8 Bi1 = (kt < 4) ? as_h8(lds[wbase + 512 + (kt << 6) + lane])
                                 : as_h8(si1[kt - 4]);
            half8 Bh0 = (kt < 4) ? as_h8(lds[wbase + ((4 + kt) << 6) + lane])
                                 : as_h8(sh0[kt - 4]);
            half8 Bh1 = (kt < 4) ? as_h8(lds[wbase + 512 + ((4 + kt) << 6) + lane])
                                 : as_h8(sh1[kt - 4]);
            if ((kt & 1) == 0) {
                ar0e = MFMA16(A, wr0[kt], ar0e);
                ar1e = MFMA16(A, wr1[kt], ar1e);
                az0e = MFMA16(A, wz0[kt], az0e);
                az1e = MFMA16(A, wz1[kt], az1e);
                ai0e = MFMA16(A, Bi0, ai0e);
                ai1e = MFMA16(A, Bi1, ai1e);
                ah0e = MFMA16(A, Bh0, ah0e);
                ah1e = MFMA16(A, Bh1, ah1e);
            } else {
                ar0o = MFMA16(A, wr0[kt], ar0o);
                ar1o = MFMA16(A, wr1[kt], ar1o);
                az0o = MFMA16(A, wz0[kt], az0o);
                az1o = MFMA16(A, wz1[kt], az1o);
                ai0o = MFMA16(A, Bi0, ai0o);
                ai1o = MFMA16(A, Bi1, ai1o);
                ah0o = MFMA16(A, Bh0, ah0o);
                ah1o = MFMA16(A, Bh1, ah1o);
            }
        }

        floatx4 ar0 = ar0e + ar0o, az0 = az0e + az0o;
        floatx4 ai0 = ai0e + ai0o, ah0 = ah0e + ah0o;
        floatx4 ar1 = ar1e + ar1o, az1 = az1e + az1o;
        floatx4 ai1 = ai1e + ai1o, ah1 = ah1e + ah1o;

        const size_t obase = (size_t)t * 1024 + r0 + (quad << 2);
        #pragma unroll
        for (int d = 0; d < 4; ++d) {
            float rr = sigm(ar0[d] + bc0.x);
            float zz = sigm(az0[d] + bc0.y);
            float nn = tanh_fast(ai0[d] + bc0.z + rr * (ah0[d] + bc0.w));
            float hnew = (1.0f - zz) * nn + zz * hreg[d];
            hreg[d] = hnew;
            unsigned short hu = f2h(hnew);
            lds_u16[wb16 + hfb0 + (d << 3)] = hu;
            Hout[((obase + d) << 8) + c0] = hu;
        }
        #pragma unroll
        for (int d = 0; d < 4; ++d) {
            float rr = sigm(ar1[d] + bc1.x);
            float zz = sigm(az1[d] + bc1.y);
            float nn = tanh_fast(ai1[d] + bc1.z + rr * (ah1[d] + bc1.w));
            float hnew = (1.0f - zz) * nn + zz * hreg[4 + d];
            hreg[4 + d] = hnew;
            unsigned short hu = f2h(hnew);
            lds_u16[wb16 + hfb1 + (d << 3)] = hu;
            Hout[((obase + d) << 8) + c1] = hu;
        }
        bar_lgkm();
    }
}

// ---------------------------------------------------------------------------
// yfused: one block per timestep t (grid 256, 1/CU, 512 thr = 8 waves).
// Phase 1: wave w computes y rows [w*128, w*128+128) x all 128 cols:
//   A-frags straight from H global (u16), B from 64KB LDS (all W_lin tiles),
//   y packed fp16 -> 32 uintx4/thread pinned in AGPRs; s1/s2 fp32 per lane.
// Phase 2: shfl + LDS reduce -> mean/scale per channel.
// Phase 3: unpack AGPR y, normalize, write fp32 out. In-place over d_out:
//   all H reads are consumed by phase-1 MFMAs before the stats barrier.
// (R11-verified, untouched)
// ---------------------------------------------------------------------------
__global__ __launch_bounds__(512, 2) void yfused_kernel(
    const uint4* __restrict__ wl, const float* __restrict__ b_lin,
    float* __restrict__ out)
{
    __shared__ uint4 bfr[4096];            // 64 KB: 64 W_lin tiles
    __shared__ float sred[8][256];         // 8 KB: per-wave s1[128] | s2[128]
    __shared__ float snorm[256];           // mean[128] | scale[128]

    const int tid  = threadIdx.x;
    const int lane = tid & 63;
    const int w    = tid >> 6;
    const int quad = lane >> 4;
    const int nc   = lane & 15;
    const int t    = blockIdx.x;

    const unsigned short* H = (const unsigned short*)out + (size_t)t * 262144;
    float* Y = out + (size_t)t * 131072;

    // stage all W_lin B-frags
    #pragma unroll
    for (int i = 0; i < 8; ++i)
        bfr[(i << 9) + tid] = wl[(i << 9) + tid];

    float blv[8];
    #pragma unroll
    for (int c = 0; c < 8; ++c) blv[c] = b_lin[(c << 4) + nc];

    __syncthreads();

    const int rw0 = w << 7;                // wave's first row of 128
    float s1[8], s2[8];
    #pragma unroll
    for (int c = 0; c < 8; ++c) { s1[c] = 0.f; s2[c] = 0.f; }
    uintx4 ypk[32];

    #pragma unroll
    for (int s = 0; s < 8; ++s) {
        const unsigned short* hrow = H + (size_t)(rw0 + (s << 4) + nc) * 256 + (quad << 3);
        uint4 A[8];
        #pragma unroll
        for (int kt = 0; kt < 8; ++kt)
            A[kt] = *(const uint4*)(hrow + (kt << 5));
        unsigned te0 = 0, te1 = 0;
        #pragma unroll
        for (int c = 0; c < 8; ++c) {
            floatx4 acc = {0.f, 0.f, 0.f, 0.f};
            #pragma unroll
            for (int kt = 0; kt < 8; ++kt)
                acc = MFMA16(as_h8(A[kt]), as_h8(bfr[(((c << 3) + kt) << 6) + lane]), acc);
            float y0 = acc[0] + blv[c], y1 = acc[1] + blv[c];
            float y2 = acc[2] + blv[c], y3 = acc[3] + blv[c];
            s1[c] += (y0 + y1) + (y2 + y3);
            s2[c] += (y0 * y0 + y1 * y1) + (y2 * y2 + y3 * y3);
            unsigned q0 = pack2h(y0, y1), q1 = pack2h(y2, y3);
            if ((c & 1) == 0) { te0 = q0; te1 = q1; }
            else {
                uintx4 v; v[0] = te0; v[1] = te1; v[2] = q0; v[3] = q1;
                asm volatile("; ypin" : "+a"(v));
                ypk[(s << 2) + (c >> 1)] = v;
            }
        }
    }

    // cross-quad then cross-wave stats reduce
    #pragma unroll
    for (int c = 0; c < 8; ++c) {
        s1[c] += __shfl_xor(s1[c], 16); s1[c] += __shfl_xor(s1[c], 32);
        s2[c] += __shfl_xor(s2[c], 16); s2[c] += __shfl_xor(s2[c], 32);
    }
    if (lane < 16) {
        #pragma unroll
        for (int c = 0; c < 8; ++c) {
            sred[w][(c << 4) + lane]       = s1[c];
            sred[w][128 + (c << 4) + lane] = s2[c];
        }
    }
    __syncthreads();
    if (tid < 128) {
        float a1 = 0.f, a2 = 0.f;
        #pragma unroll
        for (int w2 = 0; w2 < 8; ++w2) {
            a1 += sred[w2][tid];
            a2 += sred[w2][128 + tid];
        }
        float mean = a1 * (1.0f / 1024.0f);
        float var  = a2 * (1.0f / 1024.0f) - mean * mean;
        snorm[tid]       = mean;
        snorm[128 + tid] = rsqrtf(var + EPS_BN);
    }
    __syncthreads();

    float mn[8], scl[8];
    #pragma unroll
    for (int c = 0; c < 8; ++c) {
        mn[c]  = snorm[(c << 4) + nc];
        scl[c] = snorm[128 + (c << 4) + nc];
    }

    #pragma unroll
    for (int s = 0; s < 8; ++s) {
        float* yrow = Y + (size_t)(rw0 + (s << 4) + (quad << 2)) * 128 + nc;
        #pragma unroll
        for (int cp = 0; cp < 4; ++cp) {
            uintx4 v = ypk[(s << 2) + cp];
            const int c0 = cp << 1, c1 = c0 + 1;
            float2 a01 = up2(v[0]), a23 = up2(v[1]);   // col-tile c0, d0..3
            float2 b01 = up2(v[2]), b23 = up2(v[3]);   // col-tile c1, d0..3
            const int o0 = cp << 5, o1 = o0 + 16;
            yrow[0 * 128 + o0] = (a01.x - mn[c0]) * scl[c0];
            yrow[1 * 128 + o0] = (a01.y - mn[c0]) * scl[c0];
            yrow[2 * 128 + o0] = (a23.x - mn[c0]) * scl[c0];
            yrow[3 * 128 + o0] = (a23.y - mn[c0]) * scl[c0];
            yrow[0 * 128 + o1] = (b01.x - mn[c1]) * scl[c1];
            yrow[1 * 128 + o1] = (b01.y - mn[c1]) * scl[c1];
            yrow[2 * 128 + o1] = (b23.x - mn[c1]) * scl[c1];
            yrow[3 * 128 + o1] = (b23.y - mn[c1]) * scl[c1];
        }
    }
}

extern "C" void kernel_launch(void* const* d_in, const int* in_sizes, int n_in,
                              void* d_out, int out_size, void* d_ws, size_t ws_size,
                              hipStream_t stream) {
    (void)in_sizes; (void)n_in; (void)out_size; (void)ws_size;
    const float* inputs = (const float*)d_in[0];
    const float* hidden = (const float*)d_in[1];
    const float* W_ih   = (const float*)d_in[2];
    const float* b_ih   = (const float*)d_in[3];
    const float* W_hh   = (const float*)d_in[4];
    const float* b_hh   = (const float*)d_in[5];
    const float* W_lin  = (const float*)d_in[6];
    const float* b_lin  = (const float*)d_in[7];

    char* ws = (char*)d_ws;
    uint4*  wcp   = (uint4*)(ws + WS_WC);
    uint4*  w0p   = (uint4*)(ws + WS_W0);
    uint4*  wlp   = (uint4*)(ws + WS_WL);
    float4* bias0 = (float4*)(ws + WS_B0);
    float4* bcp   = (float4*)(ws + WS_BC);

    pack_all_kernel<<<418, 256, 0, stream>>>(W_ih, W_hh, W_lin, b_ih, b_hh, b_lin,
                                             w0p, wlp, bias0, wcp, bcp);
    gru_kernel<<<64, 512, 0, stream>>>(inputs, hidden, wcp, w0p, bias0, bcp, (float*)d_out);
    yfused_kernel<<<256, 512, 0, stream>>>(wlp, b_lin, (float*)d_out);
}

// Round 8
// 1002.544 us; speedup vs baseline: 1.5433x; 1.5433x over previous
//
#include <hip/hip_runtime.h>

// ---------------------------------------------------------------------------
// GRU (T=256, B=1024, IN=128, H=256) + per-step BatchNorm, MI355X.
// R13->R14: assemble best-known config, no new risk.
//   gru:      exact R9 revert (821us proven). R12 (zero-stream) and R13
//             (split accumulators) both broke the 128-VGPR streaming
//             schedule -> +56us / +548us. The R9 schedule has ZERO VGPR
//             headroom; residency map and accumulator layout are CLOSED.
//   yfused:   R11 (one block/t; y in AGPRs; stats+norm fused; no atomics).
//   pack_all: R13's 2x-parallel wc fold (not implicated in regression).
// ---------------------------------------------------------------------------

typedef _Float16 half8 __attribute__((ext_vector_type(8)));
typedef float floatx4 __attribute__((ext_vector_type(4)));
typedef unsigned uintx4 __attribute__((ext_vector_type(4)));

#define EPS_BN 1e-5f

// ws layout (bytes):
//   [0,       524288)   wc: folded gate weights, 16 cgs x 32 tiles x 1 KB
//   [524288, 1114112)   w0: step-0 weights, 16 cgs x 36 tiles x 1 KB
//   [1114112,1179648)   wl: W_lin B-frags, 64 tiles x 1 KB
//   [1179648,1183744)   bias0: 256 x float4
//   [1183744,1187840)   bc: 256 x float4 folded biases
#define WS_WC 0
#define WS_W0 524288
#define WS_WL 1114112
#define WS_B0 1179648
#define WS_BC 1183744

static __device__ __forceinline__ unsigned short f2h(float f) {
    union { _Float16 h; unsigned short u; } v;
    v.h = (_Float16)f;                      // v_cvt_f16_f32, RNE
    return v.u;
}
static __device__ __forceinline__ unsigned pack2h(float a, float b) {
    return (unsigned)f2h(a) | ((unsigned)f2h(b) << 16);
}
static __device__ __forceinline__ float2 up2(unsigned u) {
    union { unsigned v; _Float16 h[2]; } x; x.v = u;
    return make_float2((float)x.h[0], (float)x.h[1]);
}
static __device__ __forceinline__ half8 as_h8(uint4 v) {
    union { uint4 u; half8 h; } x; x.u = v; return x.h;
}
// Load a 16B weight fragment and force it into AGPRs (opaque, non-remat).
static __device__ __forceinline__ half8 ld_agpr(const uint4* p) {
    uintx4 v = *(const uintx4*)p;
    asm volatile("; wpin" : "+a"(v));
    union { uintx4 u; half8 h; } x; x.u = v; return x.h;
}
// Fast activations: v_rcp_f32 + v_exp_f32 (1 ulp each).
static __device__ __forceinline__ float sigm(float x) {
    return __builtin_amdgcn_rcpf(1.0f + __builtin_amdgcn_exp2f(-1.442695041f * x));
}
static __device__ __forceinline__ float tanh_fast(float x) {
    return 1.0f - 2.0f * __builtin_amdgcn_rcpf(1.0f + __builtin_amdgcn_exp2f(2.885390082f * x));
}
// Workgroup barrier that drains LDS only (no vmcnt(0) store-drain).
static __device__ __forceinline__ void bar_lgkm() {
    asm volatile("s_waitcnt lgkmcnt(0)\n\ts_barrier" ::: "memory");
}
#define MFMA16(A, B, C) __builtin_amdgcn_mfma_f32_16x16x32_f16((A), (B), (C), 0, 0, 0)

// ---------------------------------------------------------------------------
// pack_all: [blocks 0..160] original weights -> w0 tiles + wl + bias0;
// [blocks 161..417] folded weights -> wc tiles (ii-split x2, LDS combine)
// + folded biases bc. B-frag 16x16x32: lane l holds B[n0+(l&15)][k0+(l>>4)*8+j].
// ---------------------------------------------------------------------------
__global__ void pack_all_kernel(const float* __restrict__ W_ih, const float* __restrict__ W_hh,
                                const float* __restrict__ W_lin, const float* __restrict__ b_ih,
                                const float* __restrict__ b_hh, const float* __restrict__ b_lin,
                                uint4* __restrict__ w0, uint4* __restrict__ wl,
                                float4* __restrict__ bias0,
                                uint4* __restrict__ wc, float4* __restrict__ bc)
{
    __shared__ float sh[256][8];
    if (blockIdx.x < 161) {
        int i = blockIdx.x * 256 + threadIdx.x;
        if (i < 36864) {                       // 576 w0 tiles x 64 lanes
            int lane = i & 63, tile = i >> 6;
            int w = tile / 36, rem = tile - w * 36;
            int g = rem / 12, kt = rem - g * 12;
            int n = g * 256 + (w << 4) + (lane & 15);
            int k0 = (kt << 5) + ((lane >> 4) << 3);
            const float* p = (k0 < 128) ? (W_ih + n * 128 + k0)
                                        : (W_hh + n * 256 + (k0 - 128));
            unsigned short h[8];
            #pragma unroll
            for (int j = 0; j < 8; ++j) h[j] = f2h(p[j]);
            uint4 v;
            v.x = (unsigned)h[0] | ((unsigned)h[1] << 16);
            v.y = (unsigned)h[2] | ((unsigned)h[3] << 16);
            v.z = (unsigned)h[4] | ((unsigned)h[5] << 16);
            v.w = (unsigned)h[6] | ((unsigned)h[7] << 16);
            w0[i] = v;
        } else if (i < 40960) {                // 64 wl tiles x 64 lanes
            int i2 = i - 36864;
            int lane = i2 & 63, tile = i2 >> 6;        // tile = nt*8 + kt
            int n = (tile >> 3) * 16 + (lane & 15);
            int k0 = ((tile & 7) << 5) + ((lane >> 4) << 3);
            const float* p = W_lin + n * 256 + k0;
            unsigned short h[8];
            #pragma unroll
            for (int j = 0; j < 8; ++j) h[j] = f2h(p[j]);
            uint4 v;
            v.x = (unsigned)h[0] | ((unsigned)h[1] << 16);
            v.y = (unsigned)h[2] | ((unsigned)h[3] << 16);
            v.z = (unsigned)h[4] | ((unsigned)h[5] << 16);
            v.w = (unsigned)h[6] | ((unsigned)h[7] << 16);
            wl[i2] = v;
        } else if (i < 41216) {
            int cb = i - 40960;
            bias0[cb] = make_float4(b_ih[cb] + b_hh[cb],
                                    b_ih[256 + cb] + b_hh[256 + cb],
                                    b_ih[512 + cb], b_hh[512 + cb]);
        }
        return;
    }
    int i = (blockIdx.x - 161) * 256 + threadIdx.x;
    if (i < 65536) {                       // 512 wc tiles x 64 lanes x 2 halves
        const int tid  = threadIdx.x;
        const int lane = i & 63;
        const int half = (i >> 6) & 1;     // == (tid >> 6) & 1 (256-aligned)
        const int tile = i >> 7;
        int w = tile >> 5, r = tile & 31;
        int g = r >> 3, kt = r & 7;
        int c = (w << 4) + (lane & 15);
        int k0 = (kt << 5) + ((lane >> 4) << 3);
        float s[8];
        #pragma unroll
        for (int j = 0; j < 8; ++j) s[j] = 0.0f;
        if (g == 3) {
            if (half == 0) {
                #pragma unroll
                for (int j = 0; j < 8; ++j) s[j] = W_hh[(512 + c) * 256 + k0 + j];
            }
        } else {
            int row = g * 256 + c;
            const float* wi = W_ih + row * 128 + (half << 6);
            for (int ii = 0; ii < 64; ++ii) {
                float wv = wi[ii];
                const float* wrow = W_lin + ((half << 6) + ii) * 256 + k0;
                #pragma unroll
                for (int j = 0; j < 8; ++j) s[j] += wv * wrow[j];
            }
            if (g < 2 && half == 0) {
                #pragma unroll
                for (int j = 0; j < 8; ++j) s[j] += W_hh[row * 256 + k0 + j];
            }
        }
        #pragma unroll
        for (int j = 0; j < 8; ++j) sh[tid][j] = s[j];
        __syncthreads();
        if (half == 0) {
            #pragma unroll
            for (int j = 0; j < 8; ++j) s[j] += sh[tid + 64][j];
            unsigned short h[8];
            #pragma unroll
            for (int j = 0; j < 8; ++j) h[j] = f2h(s[j]);
            uint4 v;
            v.x = (unsigned)h[0] | ((unsigned)h[1] << 16);
            v.y = (unsigned)h[2] | ((unsigned)h[3] << 16);
            v.z = (unsigned)h[4] | ((unsigned)h[5] << 16);
            v.w = (unsigned)h[6] | ((unsigned)h[7] << 16);
            wc[tile * 64 + lane] = v;
        }
    } else if (i < 65792) {
        int c = i - 65536;
        float d0 = 0.f, d1 = 0.f, d2 = 0.f;
        for (int ii = 0; ii < 128; ++ii) {
            float bl = b_lin[ii];
            d0 += bl * W_ih[c * 128 + ii];
            d1 += bl * W_ih[(256 + c) * 128 + ii];
            d2 += bl * W_ih[(512 + c) * 128 + ii];
        }
        bc[c] = make_float4(b_ih[c] + b_hh[c] + d0,
                            b_ih[256 + c] + b_hh[256 + c] + d1,
                            b_ih[512 + c] + d2,
                            b_hh[512 + c]);
    }
}

// ---------------------------------------------------------------------------
// Recurrence: 64 blocks x 512 thr (8 waves, 2/SIMD). Block owns 16 batch
// rows; wave w owns col-groups {w, w+8} (cols c0=w*16.., c1=128+w*16..).
// Residency per wave (R9-proven map, ZERO VGPR headroom -- do not touch):
//   AGPR 32: r kt0-7, z kt0-7, both col-groups   (128 AGPRs, asm "+a" pinned)
//   LDS  16: in kt0-3, hn kt0-3, both col-groups (first-used kt<4)
//   streamed 16/step: in kt4-7, hn kt4-7 (first use kt=4 -> >=4-iter lead;
//       peak 16 live uint4 = 64 VGPRs)
// LDS (uint4): [0,1024) h-frag dbuf | [1024,1280) xbuf | [1280,9472)
// per-wave weight tiles (16/wave). One lgkm-only barrier per step.
// (exact R9 code)
// ---------------------------------------------------------------------------
__global__ __launch_bounds__(512, 2) void gru_kernel(
    const float* __restrict__ inputs,
    const float* __restrict__ hidden,
    const uint4* __restrict__ wc,
    const uint4* __restrict__ w0,
    const float4* __restrict__ bias0,
    const float4* __restrict__ bcp,
    float* __restrict__ out)
{
    __shared__ uint4 lds[9472];            // 151552 B

    const int tid  = threadIdx.x;
    const int lane = tid & 63;
    const int w    = tid >> 6;             // wave 0..7
    const int quad = lane >> 4;
    const int nc   = lane & 15;
    const int r0   = blockIdx.x << 4;
    const int c0   = (w << 4) + nc;
    const int c1   = 128 + c0;
    const float4 bc0 = bcp[c0];
    const float4 bc1 = bcp[c1];
    const uint4* wcw0 = wc + (size_t)w * 2048;        // 32 tiles * 64
    const uint4* wcw1 = wc + (size_t)(w + 8) * 2048;

    // ---- AGPR-pinned tiles: r kt0-7, z kt0-7 for both col-groups
    half8 wr0[8], wz0[8], wr1[8], wz1[8];
    #pragma unroll
    for (int kt = 0; kt < 8; ++kt) {
        wr0[kt] = ld_agpr(&wcw0[kt * 64 + lane]);
        wz0[kt] = ld_agpr(&wcw0[(8 + kt) * 64 + lane]);
        wr1[kt] = ld_agpr(&wcw1[kt * 64 + lane]);
        wz1[kt] = ld_agpr(&wcw1[(8 + kt) * 64 + lane]);
    }

    // ---- LDS-resident tiles: in kt0-3 (tiles 16-19), hn kt0-3 (tiles 24-27)
    // slot layout per cg: [0-3]=in kt0-3, [4-7]=hn kt0-3; cg1 at +512.
    const int wbase = 1280 + (w << 10);
    #pragma unroll
    for (int i = 0; i < 4; ++i) {
        lds[wbase + (i << 6) + lane]             = wcw0[(16 + i) * 64 + lane];
        lds[wbase + ((4 + i) << 6) + lane]       = wcw0[(24 + i) * 64 + lane];
        lds[wbase + 512 + (i << 6) + lane]       = wcw1[(16 + i) * 64 + lane];
        lds[wbase + 512 + ((4 + i) << 6) + lane] = wcw1[(24 + i) * 64 + lane];
    }

    // fp32 master hidden state: rows quad*4+d; [0..3]=c0, [4..7]=c1
    float hreg[8];
    #pragma unroll
    for (int d = 0; d < 4; ++d) {
        hreg[d]     = hidden[(r0 + (quad << 2) + d) * 256 + c0];
        hreg[4 + d] = hidden[(r0 + (quad << 2) + d) * 256 + c1];
    }

    // A-frag write addressing: A[m][k]: kt=k>>5, k'=k&31,
    // frag lane=(k'>>3)*16+m, j=k'&7; u16 idx=(kt*64+lane_f)*8+j
    unsigned short* lds_u16 = (unsigned short*)lds;
    const int kp  = ((w & 1) << 4) + nc;
    const int lf  = ((kp >> 3) << 4) + (quad << 2);
    const int hfb0 = (((w >> 1) * 64 + lf) << 3) + (kp & 7);
    const int hfb1 = (((4 + (w >> 1)) * 64 + lf) << 3) + (kp & 7);

    // init h(0) frags -> buf0
    for (int idx = tid; idx < 2048; idx += 512) {
        int ktl = idx >> 8;
        int rem = idx & 255;
        int lfr = rem >> 2, jg = rem & 3;
        int m = lfr & 15;
        int hc = ktl * 32 + (lfr >> 4) * 8 + jg * 2;
        const float* p = hidden + (r0 + m) * 256 + hc;
        unsigned pk = (unsigned)f2h(p[0]) | ((unsigned)f2h(p[1]) << 16);
        ((unsigned*)lds)[(ktl * 64 + lfr) * 4 + jg] = pk;
    }
    // init x frags -> xbuf
    for (int idx = tid; idx < 1024; idx += 512) {
        int kt = idx >> 8, lfr = (idx >> 2) & 63, jg = idx & 3;
        int m = lfr & 15;
        int k0 = (kt << 5) + ((lfr >> 4) << 3) + (jg << 1);
        const float* p = inputs + (r0 + m) * 128 + k0;
        unsigned pk = (unsigned)f2h(p[0]) | ((unsigned)f2h(p[1]) << 16);
        ((unsigned*)lds)[(1024 + (kt << 6) + lfr) * 4 + jg] = pk;
    }
    __syncthreads();

    unsigned short* Hout = (unsigned short*)out;

    // ---- t = 0: K=384 on [x|h] with original w0 (streamed once)
    {
        #pragma unroll
        for (int g2 = 0; g2 < 2; ++g2) {
            const uint4* ww = w0 + (size_t)(g2 ? (w + 8) : w) * 2304;  // 36*64
            floatx4 ar = {0.f,0.f,0.f,0.f}, az = {0.f,0.f,0.f,0.f};
            floatx4 ain = {0.f,0.f,0.f,0.f}, ahn = {0.f,0.f,0.f,0.f};
            #pragma unroll
            for (int kt = 0; kt < 12; ++kt) {
                half8 A = as_h8(kt < 4 ? lds[1024 + (kt << 6) + lane]
                                       : lds[((kt - 4) << 6) + lane]);
                ar = MFMA16(A, as_h8(ww[kt * 64 + lane]), ar);
                az = MFMA16(A, as_h8(ww[(12 + kt) * 64 + lane]), az);
                if (kt < 4)
                    ain = MFMA16(A, as_h8(ww[(24 + kt) * 64 + lane]), ain);
                else
                    ahn = MFMA16(A, as_h8(ww[(24 + kt) * 64 + lane]), ahn);
            }
            const int cc = g2 ? c1 : c0;
            const int hfb = g2 ? hfb1 : hfb0;
            float4 b0 = bias0[cc];
            #pragma unroll
            for (int d = 0; d < 4; ++d) {
                float rr = sigm(ar[d] + b0.x);
                float zz = sigm(az[d] + b0.y);
                float nn = tanh_fast(ain[d] + b0.z + rr * (ahn[d] + b0.w));
                float hnew = (1.0f - zz) * nn + zz * hreg[(g2 << 2) + d];
                hreg[(g2 << 2) + d] = hnew;
                unsigned short hu = f2h(hnew);
                lds_u16[4096 + hfb + (d << 3)] = hu;      // buf1
                Hout[((size_t)(r0 + (quad << 2) + d) << 8) + cc] = hu;
            }
        }
        bar_lgkm();
    }

    for (int t = 1; t < 256; ++t) {
        const int rb   = (t & 1) << 9;                 // read buf (uint4)
        const int wb16 = (((t + 1) & 1) << 9) << 3;    // write buf (u16)

        // opaque per-iteration pointers: streamed tiles cannot be hoisted
        const uint4* s0p = wcw0 + lane;
        const uint4* s1p = wcw1 + lane;
        asm("" : "+v"(s0p), "+v"(s1p));

        // streamed tiles: in kt4-7 (tiles 20-23), hn kt4-7 (tiles 28-31).
        // Batches at top and kt=1,2,3; first consumer kt=4 -> >=4-iter lead.
        uint4 si0[4], sh0[4], si1[4], sh1[4];
        si0[0] = s0p[20 * 64]; sh0[0] = s0p[28 * 64];
        si1[0] = s1p[20 * 64]; sh1[0] = s1p[28 * 64];

        floatx4 ar0 = {0.f,0.f,0.f,0.f}, az0 = {0.f,0.f,0.f,0.f};
        floatx4 ai0 = {0.f,0.f,0.f,0.f}, ah0 = {0.f,0.f,0.f,0.f};
        floatx4 ar1 = {0.f,0.f,0.f,0.f}, az1 = {0.f,0.f,0.f,0.f};
        floatx4 ai1 = {0.f,0.f,0.f,0.f}, ah1 = {0.f,0.f,0.f,0.f};

        #pragma unroll
        for (int kt = 0; kt < 8; ++kt) {
            half8 A = as_h8(lds[rb + (kt << 6) + lane]);
            if (kt == 1) {
                si0[1] = s0p[21 * 64]; sh0[1] = s0p[29 * 64];
                si1[1] = s1p[21 * 64]; sh1[1] = s1p[29 * 64];
            }
            if (kt == 2) {
                si0[2] = s0p[22 * 64]; sh0[2] = s0p[30 * 64];
                si1[2] = s1p[22 * 64]; sh1[2] = s1p[30 * 64];
            }
            if (kt == 3) {
                si0[3] = s0p[23 * 64]; sh0[3] = s0p[31 * 64];
                si1[3] = s1p[23 * 64]; sh1[3] = s1p[31 * 64];
            }
            ar0 = MFMA16(A, wr0[kt], ar0);
            ar1 = MFMA16(A, wr1[kt], ar1);
            az0 = MFMA16(A, wz0[kt], az0);
            az1 = MFMA16(A, wz1[kt], az1);
            half8 Bi0 = (kt < 4) ? as_h8(lds[wbase + (kt << 6) + lane])
                                 : as_h8(si0[kt - 4]);
            half8 Bi1 = (kt < 4) ? as_h8(lds[wbase + 512 + (kt << 6) + lane])
                                 : as_h8(si1[kt - 4]);
            ai0 = MFMA16(A, Bi0, ai0);
            ai1 = MFMA16(A, Bi1, ai1);
            half8 Bh0 = (kt < 4) ? as_h8(lds[wbase + ((4 + kt) << 6) + lane])
                                 : as_h8(sh0[kt - 4]);
            half8 Bh1 = (kt < 4) ? as_h8(lds[wbase + 512 + ((4 + kt) << 6) + lane])
                                 : as_h8(sh1[kt - 4]);
            ah0 = MFMA16(A, Bh0, ah0);
            ah1 = MFMA16(A, Bh1, ah1);
        }

        const size_t obase = (size_t)t * 1024 + r0 + (quad << 2);
        #pragma unroll
        for (int d = 0; d < 4; ++d) {
            float rr = sigm(ar0[d] + bc0.x);
            float zz = sigm(az0[d] + bc0.y);
            float nn = tanh_fast(ai0[d] + bc0.z + rr * (ah0[d] + bc0.w));
            float hnew = (1.0f - zz) * nn + zz * hreg[d];
            hreg[d] = hnew;
            unsigned short hu = f2h(hnew);
            lds_u16[wb16 + hfb0 + (d << 3)] = hu;
            Hout[((obase + d) << 8) + c0] = hu;
        }
        #pragma unroll
        for (int d = 0; d < 4; ++d) {
            float rr = sigm(ar1[d] + bc1.x);
            float zz = sigm(az1[d] + bc1.y);
            float nn = tanh_fast(ai1[d] + bc1.z + rr * (ah1[d] + bc1.w));
            float hnew = (1.0f - zz) * nn + zz * hreg[4 + d];
            hreg[4 + d] = hnew;
            unsigned short hu = f2h(hnew);
            lds_u16[wb16 + hfb1 + (d << 3)] = hu;
            Hout[((obase + d) << 8) + c1] = hu;
        }
        bar_lgkm();
    }
}

// ---------------------------------------------------------------------------
// yfused: one block per timestep t (grid 256, 1/CU, 512 thr = 8 waves).
// Phase 1: wave w computes y rows [w*128, w*128+128) x all 128 cols:
//   A-frags straight from H global (u16), B from 64KB LDS (all W_lin tiles),
//   y packed fp16 -> 32 uintx4/thread pinned in AGPRs; s1/s2 fp32 per lane.
// Phase 2: shfl + LDS reduce -> mean/scale per channel.
// Phase 3: unpack AGPR y, normalize, write fp32 out. In-place over d_out:
//   all H reads are consumed by phase-1 MFMAs before the stats barrier.
// (R11-verified, untouched)
// ---------------------------------------------------------------------------
__global__ __launch_bounds__(512, 2) void yfused_kernel(
    const uint4* __restrict__ wl, const float* __restrict__ b_lin,
    float* __restrict__ out)
{
    __shared__ uint4 bfr[4096];            // 64 KB: 64 W_lin tiles
    __shared__ float sred[8][256];         // 8 KB: per-wave s1[128] | s2[128]
    __shared__ float snorm[256];           // mean[128] | scale[128]

    const int tid  = threadIdx.x;
    const int lane = tid & 63;
    const int w    = tid >> 6;
    const int quad = lane >> 4;
    const int nc   = lane & 15;
    const int t    = blockIdx.x;

    const unsigned short* H = (const unsigned short*)out + (size_t)t * 262144;
    float* Y = out + (size_t)t * 131072;

    // stage all W_lin B-frags
    #pragma unroll
    for (int i = 0; i < 8; ++i)
        bfr[(i << 9) + tid] = wl[(i << 9) + tid];

    float blv[8];
    #pragma unroll
    for (int c = 0; c < 8; ++c) blv[c] = b_lin[(c << 4) + nc];

    __syncthreads();

    const int rw0 = w << 7;                // wave's first row of 128
    float s1[8], s2[8];
    #pragma unroll
    for (int c = 0; c < 8; ++c) { s1[c] = 0.f; s2[c] = 0.f; }
    uintx4 ypk[32];

    #pragma unroll
    for (int s = 0; s < 8; ++s) {
        const unsigned short* hrow = H + (size_t)(rw0 + (s << 4) + nc) * 256 + (quad << 3);
        uint4 A[8];
        #pragma unroll
        for (int kt = 0; kt < 8; ++kt)
            A[kt] = *(const uint4*)(hrow + (kt << 5));
        unsigned te0 = 0, te1 = 0;
        #pragma unroll
        for (int c = 0; c < 8; ++c) {
            floatx4 acc = {0.f, 0.f, 0.f, 0.f};
            #pragma unroll
            for (int kt = 0; kt < 8; ++kt)
                acc = MFMA16(as_h8(A[kt]), as_h8(bfr[(((c << 3) + kt) << 6) + lane]), acc);
            float y0 = acc[0] + blv[c], y1 = acc[1] + blv[c];
            float y2 = acc[2] + blv[c], y3 = acc[3] + blv[c];
            s1[c] += (y0 + y1) + (y2 + y3);
            s2[c] += (y0 * y0 + y1 * y1) + (y2 * y2 + y3 * y3);
            unsigned q0 = pack2h(y0, y1), q1 = pack2h(y2, y3);
            if ((c & 1) == 0) { te0 = q0; te1 = q1; }
            else {
                uintx4 v; v[0] = te0; v[1] = te1; v[2] = q0; v[3] = q1;
                asm volatile("; ypin" : "+a"(v));
                ypk[(s << 2) + (c >> 1)] = v;
            }
        }
    }

    // cross-quad then cross-wave stats reduce
    #pragma unroll
    for (int c = 0; c < 8; ++c) {
        s1[c] += __shfl_xor(s1[c], 16); s1[c] += __shfl_xor(s1[c], 32);
        s2[c] += __shfl_xor(s2[c], 16); s2[c] += __shfl_xor(s2[c], 32);
    }
    if (lane < 16) {
        #pragma unroll
        for (int c = 0; c < 8; ++c) {
            sred[w][(c << 4) + lane]       = s1[c];
            sred[w][128 + (c << 4) + lane] = s2[c];
        }
    }
    __syncthreads();
    if (tid < 128) {
        float a1 = 0.f, a2 = 0.f;
        #pragma unroll
        for (int w2 = 0; w2 < 8; ++w2) {
            a1 += sred[w2][tid];
            a2 += sred[w2][128 + tid];
        }
        float mean = a1 * (1.0f / 1024.0f);
        float var  = a2 * (1.0f / 1024.0f) - mean * mean;
        snorm[tid]       = mean;
        snorm[128 + tid] = rsqrtf(var + EPS_BN);
    }
    __syncthreads();

    float mn[8], scl[8];
    #pragma unroll
    for (int c = 0; c < 8; ++c) {
        mn[c]  = snorm[(c << 4) + nc];
        scl[c] = snorm[128 + (c << 4) + nc];
    }

    #pragma unroll
    for (int s = 0; s < 8; ++s) {
        float* yrow = Y + (size_t)(rw0 + (s << 4) + (quad << 2)) * 128 + nc;
        #pragma unroll
        for (int cp = 0; cp < 4; ++cp) {
            uintx4 v = ypk[(s << 2) + cp];
            const int c0 = cp << 1, c1 = c0 + 1;
            float2 a01 = up2(v[0]), a23 = up2(v[1]);   // col-tile c0, d0..3
            float2 b01 = up2(v[2]), b23 = up2(v[3]);   // col-tile c1, d0..3
            const int o0 = cp << 5, o1 = o0 + 16;
            yrow[0 * 128 + o0] = (a01.x - mn[c0]) * scl[c0];
            yrow[1 * 128 + o0] = (a01.y - mn[c0]) * scl[c0];
            yrow[2 * 128 + o0] = (a23.x - mn[c0]) * scl[c0];
            yrow[3 * 128 + o0] = (a23.y - mn[c0]) * scl[c0];
            yrow[0 * 128 + o1] = (b01.x - mn[c1]) * scl[c1];
            yrow[1 * 128 + o1] = (b01.y - mn[c1]) * scl[c1];
            yrow[2 * 128 + o1] = (b23.x - mn[c1]) * scl[c1];
            yrow[3 * 128 + o1] = (b23.y - mn[c1]) * scl[c1];
        }
    }
}

extern "C" void kernel_launch(void* const* d_in, const int* in_sizes, int n_in,
                              void* d_out, int out_size, void* d_ws, size_t ws_size,
                              hipStream_t stream) {
    (void)in_sizes; (void)n_in; (void)out_size; (void)ws_size;
    const float* inputs = (const float*)d_in[0];
    const float* hidden = (const float*)d_in[1];
    const float* W_ih   = (const float*)d_in[2];
    const float* b_ih   = (const float*)d_in[3];
    const float* W_hh   = (const float*)d_in[4];
    const float* b_hh   = (const float*)d_in[5];
    const float* W_lin  = (const float*)d_in[6];
    const float* b_lin  = (const float*)d_in[7];

    char* ws = (char*)d_ws;
    uint4*  wcp   = (uint4*)(ws + WS_WC);
    uint4*  w0p   = (uint4*)(ws + WS_W0);
    uint4*  wlp   = (uint4*)(ws + WS_WL);
    float4* bias0 = (float4*)(ws + WS_B0);
    float4* bcp   = (float4*)(ws + WS_BC);

    pack_all_kernel<<<418, 256, 0, stream>>>(W_ih, W_hh, W_lin, b_ih, b_hh, b_lin,
                                             w0p, wlp, bias0, wcp, bcp);
    gru_kernel<<<64, 512, 0, stream>>>(inputs, hidden, wcp, w0p, bias0, bcp, (float*)d_out);
    yfused_kernel<<<256, 512, 0, stream>>>(wlp, b_lin, (float*)d_out);
}

// Round 9
// 854.436 us; speedup vs baseline: 1.8108x; 1.1733x over previous
//
#include <hip/hip_runtime.h>

// ---------------------------------------------------------------------------
// GRU (T=256, B=1024, IN=128, H=256) + per-step BatchNorm, MI355X.
// R14->R15: gru occupancy restructure. Same 64 blocks (16 rows each), but
// 1024 thr = 16 waves = 4 waves/SIMD (was 512 thr / 2 waves/SIMD). Wave w
// owns ONE col-group (cols w*16..w*16+15). Per-wave state halves:
//   AGPR 16 tiles (64 AGPRs): r kt0-7, z kt0-7
//   LDS   8 tiles: in kt0-3, hn kt0-3          (wbase = 1280 + w*512)
//   streamed 8/step: in kt4-7, hn kt4-7 (first use kt=4; peak 32 VGPRs)
// Rationale: per-step 7700 cyc vs ~310 MFMA-issue + ~1700 LDS busy ->
// latency-convoy at 2 waves/SIMD. Doubling TLP is the one untried axis that
// RELIEVES register pressure instead of fighting it (R7/8/12/13 lesson).
// Per-SIMD MFMA work unchanged (4 waves x 32 = 2 x 64). LDS total unchanged.
// yfused (R11) and pack_all (R13) untouched.
// ---------------------------------------------------------------------------

typedef _Float16 half8 __attribute__((ext_vector_type(8)));
typedef float floatx4 __attribute__((ext_vector_type(4)));
typedef unsigned uintx4 __attribute__((ext_vector_type(4)));

#define EPS_BN 1e-5f

// ws layout (bytes):
//   [0,       524288)   wc: folded gate weights, 16 cgs x 32 tiles x 1 KB
//   [524288, 1114112)   w0: step-0 weights, 16 cgs x 36 tiles x 1 KB
//   [1114112,1179648)   wl: W_lin B-frags, 64 tiles x 1 KB
//   [1179648,1183744)   bias0: 256 x float4
//   [1183744,1187840)   bc: 256 x float4 folded biases
#define WS_WC 0
#define WS_W0 524288
#define WS_WL 1114112
#define WS_B0 1179648
#define WS_BC 1183744

static __device__ __forceinline__ unsigned short f2h(float f) {
    union { _Float16 h; unsigned short u; } v;
    v.h = (_Float16)f;                      // v_cvt_f16_f32, RNE
    return v.u;
}
static __device__ __forceinline__ unsigned pack2h(float a, float b) {
    return (unsigned)f2h(a) | ((unsigned)f2h(b) << 16);
}
static __device__ __forceinline__ float2 up2(unsigned u) {
    union { unsigned v; _Float16 h[2]; } x; x.v = u;
    return make_float2((float)x.h[0], (float)x.h[1]);
}
static __device__ __forceinline__ half8 as_h8(uint4 v) {
    union { uint4 u; half8 h; } x; x.u = v; return x.h;
}
// Load a 16B weight fragment and force it into AGPRs (opaque, non-remat).
static __device__ __forceinline__ half8 ld_agpr(const uint4* p) {
    uintx4 v = *(const uintx4*)p;
    asm volatile("; wpin" : "+a"(v));
    union { uintx4 u; half8 h; } x; x.u = v; return x.h;
}
// Fast activations: v_rcp_f32 + v_exp_f32 (1 ulp each).
static __device__ __forceinline__ float sigm(float x) {
    return __builtin_amdgcn_rcpf(1.0f + __builtin_amdgcn_exp2f(-1.442695041f * x));
}
static __device__ __forceinline__ float tanh_fast(float x) {
    return 1.0f - 2.0f * __builtin_amdgcn_rcpf(1.0f + __builtin_amdgcn_exp2f(2.885390082f * x));
}
// Workgroup barrier that drains LDS only (no vmcnt(0) store-drain).
static __device__ __forceinline__ void bar_lgkm() {
    asm volatile("s_waitcnt lgkmcnt(0)\n\ts_barrier" ::: "memory");
}
#define MFMA16(A, B, C) __builtin_amdgcn_mfma_f32_16x16x32_f16((A), (B), (C), 0, 0, 0)

// ---------------------------------------------------------------------------
// pack_all: [blocks 0..160] original weights -> w0 tiles + wl + bias0;
// [blocks 161..417] folded weights -> wc tiles (ii-split x2, LDS combine)
// + folded biases bc. B-frag 16x16x32: lane l holds B[n0+(l&15)][k0+(l>>4)*8+j].
// (R13-verified)
// ---------------------------------------------------------------------------
__global__ void pack_all_kernel(const float* __restrict__ W_ih, const float* __restrict__ W_hh,
                                const float* __restrict__ W_lin, const float* __restrict__ b_ih,
                                const float* __restrict__ b_hh, const float* __restrict__ b_lin,
                                uint4* __restrict__ w0, uint4* __restrict__ wl,
                                float4* __restrict__ bias0,
                                uint4* __restrict__ wc, float4* __restrict__ bc)
{
    __shared__ float sh[256][8];
    if (blockIdx.x < 161) {
        int i = blockIdx.x * 256 + threadIdx.x;
        if (i < 36864) {                       // 576 w0 tiles x 64 lanes
            int lane = i & 63, tile = i >> 6;
            int w = tile / 36, rem = tile - w * 36;
            int g = rem / 12, kt = rem - g * 12;
            int n = g * 256 + (w << 4) + (lane & 15);
            int k0 = (kt << 5) + ((lane >> 4) << 3);
            const float* p = (k0 < 128) ? (W_ih + n * 128 + k0)
                                        : (W_hh + n * 256 + (k0 - 128));
            unsigned short h[8];
            #pragma unroll
            for (int j = 0; j < 8; ++j) h[j] = f2h(p[j]);
            uint4 v;
            v.x = (unsigned)h[0] | ((unsigned)h[1] << 16);
            v.y = (unsigned)h[2] | ((unsigned)h[3] << 16);
            v.z = (unsigned)h[4] | ((unsigned)h[5] << 16);
            v.w = (unsigned)h[6] | ((unsigned)h[7] << 16);
            w0[i] = v;
        } else if (i < 40960) {                // 64 wl tiles x 64 lanes
            int i2 = i - 36864;
            int lane = i2 & 63, tile = i2 >> 6;        // tile = nt*8 + kt
            int n = (tile >> 3) * 16 + (lane & 15);
            int k0 = ((tile & 7) << 5) + ((lane >> 4) << 3);
            const float* p = W_lin + n * 256 + k0;
            unsigned short h[8];
            #pragma unroll
            for (int j = 0; j < 8; ++j) h[j] = f2h(p[j]);
            uint4 v;
            v.x = (unsigned)h[0] | ((unsigned)h[1] << 16);
            v.y = (unsigned)h[2] | ((unsigned)h[3] << 16);
            v.z = (unsigned)h[4] | ((unsigned)h[5] << 16);
            v.w = (unsigned)h[6] | ((unsigned)h[7] << 16);
            wl[i2] = v;
        } else if (i < 41216) {
            int cb = i - 40960;
            bias0[cb] = make_float4(b_ih[cb] + b_hh[cb],
                                    b_ih[256 + cb] + b_hh[256 + cb],
                                    b_ih[512 + cb], b_hh[512 + cb]);
        }
        return;
    }
    int i = (blockIdx.x - 161) * 256 + threadIdx.x;
    if (i < 65536) {                       // 512 wc tiles x 64 lanes x 2 halves
        const int tid  = threadIdx.x;
        const int lane = i & 63;
        const int half = (i >> 6) & 1;     // == (tid >> 6) & 1 (256-aligned)
        const int tile = i >> 7;
        int w = tile >> 5, r = tile & 31;
        int g = r >> 3, kt = r & 7;
        int c = (w << 4) + (lane & 15);
        int k0 = (kt << 5) + ((lane >> 4) << 3);
        float s[8];
        #pragma unroll
        for (int j = 0; j < 8; ++j) s[j] = 0.0f;
        if (g == 3) {
            if (half == 0) {
                #pragma unroll
                for (int j = 0; j < 8; ++j) s[j] = W_hh[(512 + c) * 256 + k0 + j];
            }
        } else {
            int row = g * 256 + c;
            const float* wi = W_ih + row * 128 + (half << 6);
            for (int ii = 0; ii < 64; ++ii) {
                float wv = wi[ii];
                const float* wrow = W_lin + ((half << 6) + ii) * 256 + k0;
                #pragma unroll
                for (int j = 0; j < 8; ++j) s[j] += wv * wrow[j];
            }
            if (g < 2 && half == 0) {
                #pragma unroll
                for (int j = 0; j < 8; ++j) s[j] += W_hh[row * 256 + k0 + j];
            }
        }
        #pragma unroll
        for (int j = 0; j < 8; ++j) sh[tid][j] = s[j];
        __syncthreads();
        if (half == 0) {
            #pragma unroll
            for (int j = 0; j < 8; ++j) s[j] += sh[tid + 64][j];
            unsigned short h[8];
            #pragma unroll
            for (int j = 0; j < 8; ++j) h[j] = f2h(s[j]);
            uint4 v;
            v.x = (unsigned)h[0] | ((unsigned)h[1] << 16);
            v.y = (unsigned)h[2] | ((unsigned)h[3] << 16);
            v.z = (unsigned)h[4] | ((unsigned)h[5] << 16);
            v.w = (unsigned)h[6] | ((unsigned)h[7] << 16);
            wc[tile * 64 + lane] = v;
        }
    } else if (i < 65792) {
        int c = i - 65536;
        float d0 = 0.f, d1 = 0.f, d2 = 0.f;
        for (int ii = 0; ii < 128; ++ii) {
            float bl = b_lin[ii];
            d0 += bl * W_ih[c * 128 + ii];
            d1 += bl * W_ih[(256 + c) * 128 + ii];
            d2 += bl * W_ih[(512 + c) * 128 + ii];
        }
        bc[c] = make_float4(b_ih[c] + b_hh[c] + d0,
                            b_ih[256 + c] + b_hh[256 + c] + d1,
                            b_ih[512 + c] + d2,
                            b_hh[512 + c]);
    }
}

// ---------------------------------------------------------------------------
// Recurrence: 64 blocks x 1024 thr (16 waves, 4/SIMD). Block owns 16 batch
// rows; wave w (0..15) owns ONE col-group: cols c0 = w*16 .. w*16+15.
// Residency per wave:
//   AGPR 16 tiles (64 AGPRs, "+a" pinned): r kt0-7, z kt0-7
//   LDS   8 tiles: in kt0-3 [slots 0-3], hn kt0-3 [slots 4-7]
//   streamed 8/step: in kt4-7 (tiles 20-23), hn kt4-7 (tiles 28-31);
//       first use kt=4 -> >=4-iter lead; peak 8 live uint4 = 32 VGPRs
// LDS (uint4): [0,1024) h-frag dbuf | [1024,1280) xbuf | [1280,9472)
// per-wave weight tiles (8/wave = 512 uint4/wave). One lgkm barrier/step.
// ---------------------------------------------------------------------------
__global__ __launch_bounds__(1024, 4) void gru_kernel(
    const float* __restrict__ inputs,
    const float* __restrict__ hidden,
    const uint4* __restrict__ wc,
    const uint4* __restrict__ w0,
    const float4* __restrict__ bias0,
    const float4* __restrict__ bcp,
    float* __restrict__ out)
{
    __shared__ uint4 lds[9472];            // 151552 B

    const int tid  = threadIdx.x;
    const int lane = tid & 63;
    const int w    = tid >> 6;             // wave 0..15
    const int quad = lane >> 4;
    const int nc   = lane & 15;
    const int r0   = blockIdx.x << 4;
    const int c0   = (w << 4) + nc;
    const float4 bc0 = bcp[c0];
    const uint4* wcw = wc + (size_t)w * 2048;         // 32 tiles * 64

    // ---- AGPR-pinned tiles: r kt0-7, z kt0-7 for this col-group
    half8 wr[8], wz[8];
    #pragma unroll
    for (int kt = 0; kt < 8; ++kt) {
        wr[kt] = ld_agpr(&wcw[kt * 64 + lane]);
        wz[kt] = ld_agpr(&wcw[(8 + kt) * 64 + lane]);
    }

    // ---- LDS-resident tiles: in kt0-3 (tiles 16-19), hn kt0-3 (tiles 24-27)
    const int wbase = 1280 + (w << 9);     // 512 uint4 per wave
    #pragma unroll
    for (int i = 0; i < 4; ++i) {
        lds[wbase + (i << 6) + lane]       = wcw[(16 + i) * 64 + lane];
        lds[wbase + ((4 + i) << 6) + lane] = wcw[(24 + i) * 64 + lane];
    }

    // fp32 master hidden state: rows quad*4+d, col c0
    float hreg[4];
    #pragma unroll
    for (int d = 0; d < 4; ++d)
        hreg[d] = hidden[(r0 + (quad << 2) + d) * 256 + c0];

    // A-frag write addressing: col c0 -> kt = w>>1, kp = (w&1)*16+nc;
    // frag lane lf = (kp>>3)*16 + quad*4; u16 idx = ((kt*64+lf)<<3)+(kp&7)
    unsigned short* lds_u16 = (unsigned short*)lds;
    const int kp  = ((w & 1) << 4) + nc;
    const int lf  = ((kp >> 3) << 4) + (quad << 2);
    const int hfb0 = (((w >> 1) * 64 + lf) << 3) + (kp & 7);

    // init h(0) frags -> buf0
    for (int idx = tid; idx < 2048; idx += 1024) {
        int ktl = idx >> 8;
        int rem = idx & 255;
        int lfr = rem >> 2, jg = rem & 3;
        int m = lfr & 15;
        int hc = ktl * 32 + (lfr >> 4) * 8 + jg * 2;
        const float* p = hidden + (r0 + m) * 256 + hc;
        unsigned pk = (unsigned)f2h(p[0]) | ((unsigned)f2h(p[1]) << 16);
        ((unsigned*)lds)[(ktl * 64 + lfr) * 4 + jg] = pk;
    }
    // init x frags -> xbuf
    if (tid < 1024) {
        int idx = tid;
        int kt = idx >> 8, lfr = (idx >> 2) & 63, jg = idx & 3;
        int m = lfr & 15;
        int k0 = (kt << 5) + ((lfr >> 4) << 3) + (jg << 1);
        const float* p = inputs + (r0 + m) * 128 + k0;
        unsigned pk = (unsigned)f2h(p[0]) | ((unsigned)f2h(p[1]) << 16);
        ((unsigned*)lds)[(1024 + (kt << 6) + lfr) * 4 + jg] = pk;
    }
    __syncthreads();

    unsigned short* Hout = (unsigned short*)out;

    // ---- t = 0: K=384 on [x|h] with original w0 (streamed once)
    {
        const uint4* ww = w0 + (size_t)w * 2304;       // 36 tiles * 64
        floatx4 ar = {0.f,0.f,0.f,0.f}, az = {0.f,0.f,0.f,0.f};
        floatx4 ain = {0.f,0.f,0.f,0.f}, ahn = {0.f,0.f,0.f,0.f};
        #pragma unroll
        for (int kt = 0; kt < 12; ++kt) {
            half8 A = as_h8(kt < 4 ? lds[1024 + (kt << 6) + lane]
                                   : lds[((kt - 4) << 6) + lane]);
            ar = MFMA16(A, as_h8(ww[kt * 64 + lane]), ar);
            az = MFMA16(A, as_h8(ww[(12 + kt) * 64 + lane]), az);
            if (kt < 4)
                ain = MFMA16(A, as_h8(ww[(24 + kt) * 64 + lane]), ain);
            else
                ahn = MFMA16(A, as_h8(ww[(24 + kt) * 64 + lane]), ahn);
        }
        float4 b0 = bias0[c0];
        #pragma unroll
        for (int d = 0; d < 4; ++d) {
            float rr = sigm(ar[d] + b0.x);
            float zz = sigm(az[d] + b0.y);
            float nn = tanh_fast(ain[d] + b0.z + rr * (ahn[d] + b0.w));
            float hnew = (1.0f - zz) * nn + zz * hreg[d];
            hreg[d] = hnew;
            unsigned short hu = f2h(hnew);
            lds_u16[4096 + hfb0 + (d << 3)] = hu;      // buf1
            Hout[((size_t)(r0 + (quad << 2) + d) << 8) + c0] = hu;
        }
        bar_lgkm();
    }

    for (int t = 1; t < 256; ++t) {
        const int rb   = (t & 1) << 9;                 // read buf (uint4)
        const int wb16 = (((t + 1) & 1) << 9) << 3;    // write buf (u16)

        // opaque per-iteration pointer: streamed tiles cannot be hoisted
        const uint4* sp = wcw + lane;
        asm("" : "+v"(sp));

        // streamed tiles: in kt4-7 (tiles 20-23), hn kt4-7 (tiles 28-31).
        uint4 si[4], sh[4];
        si[0] = sp[20 * 64]; sh[0] = sp[28 * 64];

        floatx4 ar = {0.f,0.f,0.f,0.f}, az = {0.f,0.f,0.f,0.f};
        floatx4 ai = {0.f,0.f,0.f,0.f}, ah = {0.f,0.f,0.f,0.f};

        #pragma unroll
        for (int kt = 0; kt < 8; ++kt) {
            half8 A = as_h8(lds[rb + (kt << 6) + lane]);
            if (kt == 1) { si[1] = sp[21 * 64]; sh[1] = sp[29 * 64]; }
            if (kt == 2) { si[2] = sp[22 * 64]; sh[2] = sp[30 * 64]; }
            if (kt == 3) { si[3] = sp[23 * 64]; sh[3] = sp[31 * 64]; }
            ar = MFMA16(A, wr[kt], ar);
            az = MFMA16(A, wz[kt], az);
            half8 Bi = (kt < 4) ? as_h8(lds[wbase + (kt << 6) + lane])
                                : as_h8(si[kt - 4]);
            ai = MFMA16(A, Bi, ai);
            half8 Bh = (kt < 4) ? as_h8(lds[wbase + ((4 + kt) << 6) + lane])
                                : as_h8(sh[kt - 4]);
            ah = MFMA16(A, Bh, ah);
        }

        const size_t obase = (size_t)t * 1024 + r0 + (quad << 2);
        #pragma unroll
        for (int d = 0; d < 4; ++d) {
            float rr = sigm(ar[d] + bc0.x);
            float zz = sigm(az[d] + bc0.y);
            float nn = tanh_fast(ai[d] + bc0.z + rr * (ah[d] + bc0.w));
            float hnew = (1.0f - zz) * nn + zz * hreg[d];
            hreg[d] = hnew;
            unsigned short hu = f2h(hnew);
            lds_u16[wb16 + hfb0 + (d << 3)] = hu;
            Hout[((obase + d) << 8) + c0] = hu;
        }
        bar_lgkm();
    }
}

// ---------------------------------------------------------------------------
// yfused: one block per timestep t (grid 256, 1/CU, 512 thr = 8 waves).
// Phase 1: wave w computes y rows [w*128, w*128+128) x all 128 cols:
//   A-frags straight from H global (u16), B from 64KB LDS (all W_lin tiles),
//   y packed fp16 -> 32 uintx4/thread pinned in AGPRs; s1/s2 fp32 per lane.
// Phase 2: shfl + LDS reduce -> mean/scale per channel.
// Phase 3: unpack AGPR y, normalize, write fp32 out. In-place over d_out:
//   all H reads are consumed by phase-1 MFMAs before the stats barrier.
// (R11-verified, untouched)
// ---------------------------------------------------------------------------
__global__ __launch_bounds__(512, 2) void yfused_kernel(
    const uint4* __restrict__ wl, const float* __restrict__ b_lin,
    float* __restrict__ out)
{
    __shared__ uint4 bfr[4096];            // 64 KB: 64 W_lin tiles
    __shared__ float sred[8][256];         // 8 KB: per-wave s1[128] | s2[128]
    __shared__ float snorm[256];           // mean[128] | scale[128]

    const int tid  = threadIdx.x;
    const int lane = tid & 63;
    const int w    = tid >> 6;
    const int quad = lane >> 4;
    const int nc   = lane & 15;
    const int t    = blockIdx.x;

    const unsigned short* H = (const unsigned short*)out + (size_t)t * 262144;
    float* Y = out + (size_t)t * 131072;

    // stage all W_lin B-frags
    #pragma unroll
    for (int i = 0; i < 8; ++i)
        bfr[(i << 9) + tid] = wl[(i << 9) + tid];

    float blv[8];
    #pragma unroll
    for (int c = 0; c < 8; ++c) blv[c] = b_lin[(c << 4) + nc];

    __syncthreads();

    const int rw0 = w << 7;                // wave's first row of 128
    float s1[8], s2[8];
    #pragma unroll
    for (int c = 0; c < 8; ++c) { s1[c] = 0.f; s2[c] = 0.f; }
    uintx4 ypk[32];

    #pragma unroll
    for (int s = 0; s < 8; ++s) {
        const unsigned short* hrow = H + (size_t)(rw0 + (s << 4) + nc) * 256 + (quad << 3);
        uint4 A[8];
        #pragma unroll
        for (int kt = 0; kt < 8; ++kt)
            A[kt] = *(const uint4*)(hrow + (kt << 5));
        unsigned te0 = 0, te1 = 0;
        #pragma unroll
        for (int c = 0; c < 8; ++c) {
            floatx4 acc = {0.f, 0.f, 0.f, 0.f};
            #pragma unroll
            for (int kt = 0; kt < 8; ++kt)
                acc = MFMA16(as_h8(A[kt]), as_h8(bfr[(((c << 3) + kt) << 6) + lane]), acc);
            float y0 = acc[0] + blv[c], y1 = acc[1] + blv[c];
            float y2 = acc[2] + blv[c], y3 = acc[3] + blv[c];
            s1[c] += (y0 + y1) + (y2 + y3);
            s2[c] += (y0 * y0 + y1 * y1) + (y2 * y2 + y3 * y3);
            unsigned q0 = pack2h(y0, y1), q1 = pack2h(y2, y3);
            if ((c & 1) == 0) { te0 = q0; te1 = q1; }
            else {
                uintx4 v; v[0] = te0; v[1] = te1; v[2] = q0; v[3] = q1;
                asm volatile("; ypin" : "+a"(v));
                ypk[(s << 2) + (c >> 1)] = v;
            }
        }
    }

    // cross-quad then cross-wave stats reduce
    #pragma unroll
    for (int c = 0; c < 8; ++c) {
        s1[c] += __shfl_xor(s1[c], 16); s1[c] += __shfl_xor(s1[c], 32);
        s2[c] += __shfl_xor(s2[c], 16); s2[c] += __shfl_xor(s2[c], 32);
    }
    if (lane < 16) {
        #pragma unroll
        for (int c = 0; c < 8; ++c) {
            sred[w][(c << 4) + lane]       = s1[c];
            sred[w][128 + (c << 4) + lane] = s2[c];
        }
    }
    __syncthreads();
    if (tid < 128) {
        float a1 = 0.f, a2 = 0.f;
        #pragma unroll
        for (int w2 = 0; w2 < 8; ++w2) {
            a1 += sred[w2][tid];
            a2 += sred[w2][128 + tid];
        }
        float mean = a1 * (1.0f / 1024.0f);
        float var  = a2 * (1.0f / 1024.0f) - mean * mean;
        snorm[tid]       = mean;
        snorm[128 + tid] = rsqrtf(var + EPS_BN);
    }
    __syncthreads();

    float mn[8], scl[8];
    #pragma unroll
    for (int c = 0; c < 8; ++c) {
        mn[c]  = snorm[(c << 4) + nc];
        scl[c] = snorm[128 + (c << 4) + nc];
    }

    #pragma unroll
    for (int s = 0; s < 8; ++s) {
        float* yrow = Y + (size_t)(rw0 + (s << 4) + (quad << 2)) * 128 + nc;
        #pragma unroll
        for (int cp = 0; cp < 4; ++cp) {
            uintx4 v = ypk[(s << 2) + cp];
            const int c0 = cp << 1, c1 = c0 + 1;
            float2 a01 = up2(v[0]), a23 = up2(v[1]);   // col-tile c0, d0..3
            float2 b01 = up2(v[2]), b23 = up2(v[3]);   // col-tile c1, d0..3
            const int o0 = cp << 5, o1 = o0 + 16;
            yrow[0 * 128 + o0] = (a01.x - mn[c0]) * scl[c0];
            yrow[1 * 128 + o0] = (a01.y - mn[c0]) * scl[c0];
            yrow[2 * 128 + o0] = (a23.x - mn[c0]) * scl[c0];
            yrow[3 * 128 + o0] = (a23.y - mn[c0]) * scl[c0];
            yrow[0 * 128 + o1] = (b01.x - mn[c1]) * scl[c1];
            yrow[1 * 128 + o1] = (b01.y - mn[c1]) * scl[c1];
            yrow[2 * 128 + o1] = (b23.x - mn[c1]) * scl[c1];
            yrow[3 * 128 + o1] = (b23.y - mn[c1]) * scl[c1];
        }
    }
}

extern "C" void kernel_launch(void* const* d_in, const int* in_sizes, int n_in,
                              void* d_out, int out_size, void* d_ws, size_t ws_size,
                              hipStream_t stream) {
    (void)in_sizes; (void)n_in; (void)out_size; (void)ws_size;
    const float* inputs = (const float*)d_in[0];
    const float* hidden = (const float*)d_in[1];
    const float* W_ih   = (const float*)d_in[2];
    const float* b_ih   = (const float*)d_in[3];
    const float* W_hh   = (const float*)d_in[4];
    const float* b_hh   = (const float*)d_in[5];
    const float* W_lin  = (const float*)d_in[6];
    const float* b_lin  = (const float*)d_in[7];

    char* ws = (char*)d_ws;
    uint4*  wcp   = (uint4*)(ws + WS_WC);
    uint4*  w0p   = (uint4*)(ws + WS_W0);
    uint4*  wlp   = (uint4*)(ws + WS_WL);
    float4* bias0 = (float4*)(ws + WS_B0);
    float4* bcp   = (float4*)(ws + WS_BC);

    pack_all_kernel<<<418, 256, 0, stream>>>(W_ih, W_hh, W_lin, b_ih, b_hh, b_lin,
                                             w0p, wlp, bias0, wcp, bcp);
    gru_kernel<<<64, 1024, 0, stream>>>(inputs, hidden, wcp, w0p, bias0, bcp, (float*)d_out);
    yfused_kernel<<<256, 512, 0, stream>>>(wlp, b_lin, (float*)d_out);
}